// Round 5
// baseline (76.829 us; speedup 1.0000x reference)
//
#include <hip/hip_runtime.h>
#include <math.h>

// KANConv2D via bf16 MFMA, R11.
// R11: switch 16x16x32 -> 32x32x16 MFMA and re-cut the wave cube to halve
// LDS A-read traffic (the R10 bottleneck: 4 nq waves read identical A).
// - Main: 196 blocks (4 b x 7x7 tiles of 8x8 px, M=64), 512 thr = 8 waves:
//   wave = (nqq 0..1: 32-oc half) x (kq 0..3: K quarter, 36 K16-steps).
//   Each wave: 2 row-frags (mq) x 1 col-frag of 32x32, A read by only 2
//   waves (nqq pair) -> A-LDS 1152 -> 576 KB/block. B unique per block
//   (288 KB L2). Base conv (K=288) done entirely by kq=0 waves -> no base
//   reduction; spline 4-way K-reduction in one 48 KB LDS round.
// - cvt kernel emits 32-col B-frag streams for 32x32x16 layout.
// Frag maps (32x32x16, canonical CDNA4; C/D verified m74/m101):
//   A: m = lane&31 (+32mq), k = (lane>>5)*8 + j
//   B: n = lane&31, k = (lane>>5)*8 + j
//   C/D: col = lane&31 = n, row = (reg&3) + 8*(reg>>2) + 4*(lane>>5) (+32mq)
// Base conv k-order = tap*32 + c (tap-major) -> A read directly from raw-x
// halo xh, no im2col scatter (R10). Spline k-order = p*8 + basis.

typedef __attribute__((ext_vector_type(8))) short bf16x8;
typedef __attribute__((ext_vector_type(4))) float f32x4;
typedef __attribute__((ext_vector_type(16))) float f32x16;

#define MFMA32(a, b, c) __builtin_amdgcn_mfma_f32_32x32x16_bf16((a), (b), (c), 0, 0, 0)

__device__ __forceinline__ unsigned short f2bf(float f) {
    unsigned u = __builtin_bit_cast(unsigned, f);
    u = (u + 0x7fffu + ((u >> 16) & 1u)) >> 16;   // RNE
    return (unsigned short)u;
}

__device__ __forceinline__ void eval_bases(float v, float bs[8]) {
    #pragma unroll
    for (int i = 0; i < 8; ++i) bs[i] = 0.0f;
    // knots: t_g = (g-3)*0.4 - 1, support [-2.2, 2.2)
    float t = (v + 2.2f) * 2.5f;
    if (t >= 0.0f && t < 11.0f) {
        int j = (int)t;
        if (j > 10) j = 10;
        float knot = (float)(j - 3) * 0.4f - 1.0f;
        float u  = (v - knot) * 2.5f;
        float um = 1.0f - u;
        float u2 = u * u, u3 = u2 * u;
        const float s6 = 1.0f / 6.0f;
        float w0 = um * um * um * s6;
        float w1 = (3.0f * u3 - 6.0f * u2 + 4.0f) * s6;
        float w2 = (-3.0f * u3 + 3.0f * u2 + 3.0f * u + 1.0f) * s6;
        float w3 = u3 * s6;
        int i0 = j - 3;
        if (i0 >= 0)               bs[i0]     = w0;
        if (i0 + 1 >= 0 && i0 < 7) bs[i0 + 1] = w1;
        if (i0 + 2 >= 0 && i0 < 6) bs[i0 + 2] = w2;
        if (i0 + 3 <= 7)           bs[i0 + 3] = w3;
    }
}

// ---- pre-kernel: fp32 weights -> bf16 32-col B-frag streams ----
// wst[((nqq*144+t)*64+l)*8+j] = ws[(nqq*32+(l&31))*2304 + t*16 + (l>>5)*8 + j]
// wbt[((nqq*18 +t)*64+l)*8+j] = wb[(nqq*32+(l&31))*288 + c*9 + tap],
//   where tap = t>>1, c = 16*(t&1) + (l>>5)*8 + j   (k-order = tap*32 + c)
__global__ __launch_bounds__(256)
void cvt_swz_kernel(const float* __restrict__ ws, const float* __restrict__ wb,
                    unsigned short* __restrict__ wst, unsigned short* __restrict__ wbt) {
    int i = blockIdx.x * 256 + threadIdx.x;
    if (i < 147456) {
        int j = i & 7, l = (i >> 3) & 63, tq = i >> 9;   // tq 0..287
        int t = tq % 144, nqq = tq / 144;
        int oc = nqq * 32 + (l & 31);
        int k  = t * 16 + (l >> 5) * 8 + j;
        wst[i] = f2bf(ws[oc * 2304 + k]);
    } else {
        int i2 = i - 147456;
        if (i2 < 18432) {
            int j = i2 & 7, l = (i2 >> 3) & 63, tq = i2 >> 9;  // tq 0..35
            int t = tq % 18, nqq = tq / 18;
            int oc  = nqq * 32 + (l & 31);
            int tap = t >> 1;
            int c   = 16 * (t & 1) + (l >> 5) * 8 + j;
            wbt[i2] = f2bf(wb[oc * 288 + c * 9 + tap]);
        }
    }
}

__global__ __launch_bounds__(512)
void kan_mfma_kernel(const float* __restrict__ x,
                     const float* __restrict__ sc,
                     const unsigned short* __restrict__ wst,
                     const unsigned short* __restrict__ wbt,
                     float* __restrict__ out) {
    // sb: bases [c 0..31][hp 0..99][8]   = 25600 us (51200 B)
    // xh: raw x [hp 0..99][40: 32 c+pad] =  4000 us ( 8000 B)  total 59200 B
    __shared__ unsigned short smem[29600];
    unsigned short* sb = smem;
    unsigned short* xh = smem + 25600;

    const int tid = threadIdx.x;
    const int bx  = blockIdx.x;              // 0..195
    const int b   = bx / 49;
    const int r   = bx - b * 49;
    const int ty  = r / 7;
    const int tx  = r - ty * 7;
    const int h0  = ty * 8, w0 = tx * 8;

    const int lane = tid & 63;
    const int wv   = tid >> 6;        // 0..7
    const int nqq  = wv & 1;          // oc half (32 oc)
    const int kq   = wv >> 1;         // K quarter (36 K16-steps)
    const int hl   = lane >> 5;       // k-group 0..1 within k16 step
    const int rl   = lane & 31;       // A row within frag / B,C col
    const int py   = rl >> 3, px = rl & 7;   // frag-0 pixel (rows 0..31)

    // ---- phase 1: 3200 halo elems (10x10x32), batched loads, 1 store each ----
    float vv[7];
    #pragma unroll
    for (int j = 0; j < 7; ++j) {
        int i = tid + j * 512;        // 0..3583
        float val = 0.0f;
        if (i < 3200) {
            int c  = i / 100;
            int hp = i - c * 100;
            int hy = hp / 10;
            int hx = hp - hy * 10;
            int hh = h0 + hy - 1, ww = w0 + hx - 1;
            if ((unsigned)hh < 56u && (unsigned)ww < 56u)
                val = x[((b * 32 + c) * 56 + hh) * 56 + ww];
        }
        vv[j] = val;
    }
    #pragma unroll
    for (int j = 0; j < 7; ++j) {
        int i = tid + j * 512;
        if (i < 3200) {
            int c  = i / 100;
            int hp = i - c * 100;
            float bs[8];
            eval_bases(vv[j], bs);
            bf16x8 pk;
            #pragma unroll
            for (int j2 = 0; j2 < 8; ++j2) pk[j2] = (short)f2bf(bs[j2]);
            *reinterpret_cast<bf16x8*>(&sb[i * 8]) = pk;   // i = c*100+hp
            xh[hp * 40 + c] = f2bf(vv[j]);
        }
    }
    __syncthreads();

    // spline A offsets (ushort units): step t reads patch-pos p = 2t + hl.
    // Within a 9-step u-group: tt = 2u + hl (0..17): dc = tt/9, tap = tt%9.
    // mq frag (rows 32..63) = +4 tile rows = +320 ushorts.
    int aoff2[9];
    #pragma unroll
    for (int u = 0; u < 9; ++u) {
        int tt  = 2 * u + hl;         // 0..17
        int dc  = tt >= 9 ? 1 : 0;
        int tap = tt - 9 * dc;
        int th  = tap / 3;
        int tw  = tap - th * 3;
        aoff2[u] = (dc * 100 + (py + th) * 10 + (px + tw)) * 8;
    }

    f32x16 accS0 = {0,0,0,0,0,0,0,0,0,0,0,0,0,0,0,0};
    f32x16 accS1 = {0,0,0,0,0,0,0,0,0,0,0,0,0,0,0,0};

    // ---- spline GEMM: this wave's 36 K16-steps (t = kq*36 + a*9 + u) ----
    // per step: 1 B global load, 2 A LDS reads (mq 0,1), 2 MFMA.
    const unsigned short* bp = wst + ((nqq * 144 + kq * 36) * 64 + lane) * 8;
    for (int a = 0; a < 4; ++a) {
        const int cbase = (kq * 8 + 2 * a) * 800;   // c-base * 100 hp * 8
        #pragma unroll
        for (int u = 0; u < 9; ++u) {
            bf16x8 bw = *reinterpret_cast<const bf16x8*>(bp + (a * 9 + u) * 512);
            bf16x8 a0 = *reinterpret_cast<const bf16x8*>(&sb[cbase + aoff2[u]]);
            bf16x8 a1 = *reinterpret_cast<const bf16x8*>(&sb[cbase + aoff2[u] + 320]);
            accS0 = MFMA32(a0, bw, accS0);
            accS1 = MFMA32(a1, bw, accS1);
        }
    }

    // ---- base GEMM (K=288, 18 K16-steps): kq==0 waves only, no reduction ----
    f32x16 accB0 = {0,0,0,0,0,0,0,0,0,0,0,0,0,0,0,0};
    f32x16 accB1 = {0,0,0,0,0,0,0,0,0,0,0,0,0,0,0,0};
    if (kq == 0) {
        const unsigned short* bbp = wbt + (nqq * 18 * 64 + lane) * 8;
        const int c0 = hl * 8;
        #pragma unroll
        for (int t = 0; t < 18; ++t) {
            const int tap = t >> 1, th = tap / 3, tw = tap - 3 * th;  // const-folded
            bf16x8 bw = *reinterpret_cast<const bf16x8*>(bbp + t * 512);
            int xa = ((py + th) * 10 + (px + tw)) * 40 + 16 * (t & 1) + c0;
            bf16x8 a0 = *reinterpret_cast<const bf16x8*>(&xh[xa]);
            bf16x8 a1 = *reinterpret_cast<const bf16x8*>(&xh[xa + 1600]);
            accB0 = MFMA32(a0, bw, accB0);
            accB1 = MFMA32(a1, bw, accB1);
        }
    }

    // ---- spline 4-way K reduction via LDS (3 regions x 16 KB, one round) ----
    __syncthreads();                               // all sb/xh reads done
    float* red = reinterpret_cast<float*>(smem);   // 3*4096 f32 = 48 KB
    const int col = nqq * 64 + lane;               // 0..127 within kq group
    if (kq) {
        const int rb = (kq - 1) * 4096;
        #pragma unroll
        for (int w = 0; w < 16; ++w) red[rb + w * 128 + col] = accS0[w];
        #pragma unroll
        for (int w = 0; w < 16; ++w) red[rb + (16 + w) * 128 + col] = accS1[w];
    }
    __syncthreads();
    if (kq == 0) {
        #pragma unroll
        for (int rr = 0; rr < 3; ++rr) {
            const int rb = rr * 4096;
            #pragma unroll
            for (int w = 0; w < 16; ++w) accS0[w] += red[rb + w * 128 + col];
            #pragma unroll
            for (int w = 0; w < 16; ++w) accS1[w] += red[rb + (16 + w) * 128 + col];
        }

        // ---- epilogue: row = (reg&3) + 8*(reg>>2) + 4*hl (+32mq) ----
        //   -> py_o = mq*4 + (reg>>2), px_o = 4*hl + (reg&3): f32x4 per quad.
        const int oc  = nqq * 32 + rl;
        const float scv = sc[oc];
        #pragma unroll
        for (int mq = 0; mq < 2; ++mq) {
            f32x16 aS = mq ? accS1 : accS0;
            f32x16 aB = mq ? accB1 : accB0;
            #pragma unroll
            for (int q = 0; q < 4; ++q) {
                float* ob = out + ((b * 64 + oc) * 56 + h0 + mq * 4 + q) * 56 + w0 + 4 * hl;
                f32x4 res;
                #pragma unroll
                for (int rr = 0; rr < 4; ++rr) {
                    float bv = aB[q * 4 + rr];
                    float si = bv / (1.0f + __expf(-bv));
                    res[rr] = si + scv * aS[q * 4 + rr];
                }
                *reinterpret_cast<f32x4*>(ob) = res;
            }
        }
    }
}

extern "C" void kernel_launch(void* const* d_in, const int* in_sizes, int n_in,
                              void* d_out, int out_size, void* d_ws, size_t ws_size,
                              hipStream_t stream) {
    const float* x  = (const float*)d_in[0];   // (4,32,56,56)
    const float* wb = (const float*)d_in[1];   // (64,32,3,3)
    const float* ws = (const float*)d_in[2];   // (64,288,8)
    const float* sc = (const float*)d_in[3];   // (64,)
    float* out = (float*)d_out;                // (4,64,56,56)

    unsigned short* wst = (unsigned short*)d_ws;   // 147456 bf16
    unsigned short* wbt = wst + 147456;            // 18432 bf16

    cvt_swz_kernel<<<648, 256, 0, stream>>>(ws, wb, wst, wbt);
    kan_mfma_kernel<<<196, 512, 0, stream>>>(x, sc, wst, wbt, out);
}